// Round 5
// baseline (160.157 us; speedup 1.0000x reference)
//
#include <hip/hip_runtime.h>

// Involution2d, 3-kernel split, transpose-free MFMA GEMM.
// K0: x f32 [b][ch][px] -> xT bf16 [b][px][ch] (LDS transpose); w -> bf16.
// K1: kern[b][784][4096] = W(784x256) @ x[b](256x4096) + bias.
//     Both operands fragment-shaped in global: A=W[m][ch], B=xT[px][ch],
//     16B contiguous per lane. No LDS, no barriers, double-buffered frags.
// K2: out[b][g*16+c][p] = sum_{7x7} x[b][g*16+c][p+off] * kern[b][g*49+koff][p]

#define B_   4
#define C_   256
#define HW_  4096
#define G_   16
#define KK_  49
#define M_   784
#define KS_  7
#define PD_  3

#define KERN_BYTES  (B_*M_*HW_*2)            // 25,690,112
#define XT_BYTES    (B_*HW_*C_*2)            //  8,388,608
#define XT_OFF      KERN_BYTES
#define WBF_OFF     (KERN_BYTES + XT_BYTES)

typedef __attribute__((ext_vector_type(8))) short bf16x8;
typedef __attribute__((ext_vector_type(4))) float f32x4;
typedef unsigned short ushort_t;

__device__ inline unsigned f2bf(float f) {            // RNE fp32->bf16
    unsigned u = __float_as_uint(f);
    u += 0x7FFF + ((u >> 16) & 1);
    return u >> 16;
}
__device__ inline float bf2f(unsigned short s) {
    return __uint_as_float(((unsigned)s) << 16);
}

// ---------------- K0: transpose-convert x -> xT bf16; convert w ----------------
// grid (65, 4, 4): x<64 -> 64px x 64ch tile of batch z; x==64 -> 1/16 of W.
__global__ __launch_bounds__(256)
void cvt_xT(const float* __restrict__ x, const float* __restrict__ wk,
            ushort_t* __restrict__ xT, unsigned* __restrict__ wbf) {
    const int t = threadIdx.x;
    if (blockIdx.x == 64) {   // W convert: 100352 f32 pairs total, 16 slices
        const int slice = blockIdx.z * 4 + blockIdx.y;
        const float2* wk2 = (const float2*)wk;
        const int base = slice * 6272;
        for (int k = t; k < 6272; k += 256) {
            float2 v = wk2[base + k];
            wbf[base + k] = f2bf(v.x) | (f2bf(v.y) << 16);
        }
        return;
    }
    __shared__ float tile[64][65];
    const int p0 = blockIdx.x * 64;
    const int c0 = blockIdx.y * 64;
    const int b  = blockIdx.z;
    const int px_r = t & 63;
    #pragma unroll
    for (int i = 0; i < 16; ++i) {
        int ch = (t >> 6) + i * 4;
        tile[ch][px_r] = x[((size_t)(b * C_ + c0 + ch) << 12) + p0 + px_r];
    }
    __syncthreads();
    const int px  = t >> 2;
    const int seg = t & 3;
    unsigned u[8];
    #pragma unroll
    for (int j = 0; j < 8; ++j) {
        float a0 = tile[seg * 16 + 2 * j][px];
        float a1 = tile[seg * 16 + 2 * j + 1][px];
        u[j] = f2bf(a0) | (f2bf(a1) << 16);
    }
    unsigned* dst = (unsigned*)(xT + ((size_t)((b << 12) + p0 + px)) * C_ + c0 + seg * 16);
    ((uint4*)dst)[0] = make_uint4(u[0], u[1], u[2], u[3]);
    ((uint4*)dst)[1] = make_uint4(u[4], u[5], u[6], u[7]);
}

// ---------------- K1: kern GEMM, LDS-free, barrier-free ----------------
// grid (32, 7, 4). Block 4 waves; wave w: m-rows mb*112..+111 (7 tiles),
// n-cols nb*128 + w*32 (2 tiles). Double-buffered frags, 14 MFMA/chunk.
__global__ __launch_bounds__(256, 3)
void kern_gemm(const ushort_t* __restrict__ xT,
               const ushort_t* __restrict__ wbf,
               const float* __restrict__ bk,
               ushort_t* __restrict__ kern) {
    const int nb = blockIdx.x, mb = blockIdx.y, bb = blockIdx.z;
    const int tid  = threadIdx.x;
    const int wv   = tid >> 6;
    const int lane = tid & 63;
    const int ln15 = lane & 15;
    const int quad = lane >> 4;

    const int m0 = mb * 112;
    const int n0 = nb * 128 + wv * 32;

    f32x4 acc[14];
    #pragma unroll
    for (int i = 0; i < 14; ++i) acc[i] = (f32x4){0.f, 0.f, 0.f, 0.f};

    const ushort_t* ap = wbf + (size_t)(m0 + ln15) * C_ + quad * 8;
    const ushort_t* bp = xT + ((size_t)((bb << 12) + n0 + ln15)) * C_ + quad * 8;

    bf16x8 af[2][7], bf[2][2];
    #pragma unroll
    for (int mt = 0; mt < 7; ++mt) af[0][mt] = *(const bf16x8*)(ap + mt * 16 * C_);
    #pragma unroll
    for (int nt = 0; nt < 2; ++nt) bf[0][nt] = *(const bf16x8*)(bp + nt * 16 * C_);

    #pragma unroll
    for (int k = 0; k < 8; ++k) {
        const int cur = k & 1, nxt = cur ^ 1;
        if (k < 7) {
            const int cc = (k + 1) * 32;
            #pragma unroll
            for (int mt = 0; mt < 7; ++mt)
                af[nxt][mt] = *(const bf16x8*)(ap + mt * 16 * C_ + cc);
            #pragma unroll
            for (int nt = 0; nt < 2; ++nt)
                bf[nxt][nt] = *(const bf16x8*)(bp + nt * 16 * C_ + cc);
        }
        #pragma unroll
        for (int mt = 0; mt < 7; ++mt) {
            #pragma unroll
            for (int nt = 0; nt < 2; ++nt) {
                acc[mt * 2 + nt] = __builtin_amdgcn_mfma_f32_16x16x32_bf16(
                    af[cur][mt], bf[cur][nt], acc[mt * 2 + nt], 0, 0, 0);
            }
        }
    }

    // epilogue: D[m=quad*4+r][n=ln15]; bias, round, store bf16
    #pragma unroll
    for (int mt = 0; mt < 7; ++mt) {
        #pragma unroll
        for (int r = 0; r < 4; ++r) {
            const int m = m0 + mt * 16 + quad * 4 + r;
            const float bias = bk[m];
            #pragma unroll
            for (int nt = 0; nt < 2; ++nt) {
                float v = acc[mt * 2 + nt][r] + bias;
                kern[((size_t)(bb * M_ + m) << 12) + n0 + nt * 16 + ln15] =
                    (ushort_t)f2bf(v);
            }
        }
    }
}

// ---------------- K2: apply involution ----------------
// 512 threads; block = 8 rows x 64 px, one full group (16 ch, 2 halo batches).
// grid (8, 16, 4) = 512 blocks. LDS halo [8][14][72] f32 = 32.2KB.
__global__ __launch_bounds__(512)
void inv_apply(const float* __restrict__ x,
               const ushort_t* __restrict__ kern,
               float* __restrict__ out) {
    __shared__ float halo[8 * 14 * 72];

    const int gy0 = blockIdx.x * 8;
    const int g   = blockIdx.y;
    const int b   = blockIdx.z;
    const int tid = threadIdx.x;
    const int py  = tid >> 6;
    const int px  = tid & 63;

    // 49 kernel values for this pixel (coalesced: 128B/wave rows)
    float kernv[KK_];
    const ushort_t* kb = kern + ((size_t)(b * M_ + g * KK_) << 12) + gy0 * 64 + tid;
    #pragma unroll
    for (int j = 0; j < KK_; ++j) kernv[j] = bf2f(kb[(size_t)j << 12]);

    #pragma unroll 1
    for (int hb = 0; hb < 2; ++hb) {
        if (hb) __syncthreads();
        const int cbase = g * 16 + hb * 8;
        for (int e = tid; e < 8 * 14 * 70; e += 512) {
            int ch  = e / (14 * 70);
            int rem = e - ch * (14 * 70);
            int hy  = rem / 70;
            int hx  = rem - hy * 70;
            int sy  = gy0 + hy - PD_;
            int sx  = hx - PD_;
            float v = 0.f;
            if (sy >= 0 && sy < 64 && sx >= 0 && sx < 64)
                v = x[((size_t)(b * C_ + cbase + ch) << 12) + sy * 64 + sx];
            halo[ch * (14 * 72) + hy * 72 + hx] = v;
        }
        __syncthreads();

        #pragma unroll 1
        for (int c = 0; c < 8; ++c) {
            const float* xs = &halo[c * (14 * 72) + py * 72 + px];
            float a = 0.f;
            #pragma unroll
            for (int kh = 0; kh < KS_; ++kh) {
                #pragma unroll
                for (int kw = 0; kw < KS_; ++kw) {
                    a = fmaf(xs[kh * 72 + kw], kernv[kh * KS_ + kw], a);
                }
            }
            out[((size_t)(b * C_ + cbase + c) << 12) + gy0 * 64 + tid] = a;
        }
    }
}

extern "C" void kernel_launch(void* const* d_in, const int* in_sizes, int n_in,
                              void* d_out, int out_size, void* d_ws, size_t ws_size,
                              hipStream_t stream) {
    const float* x  = (const float*)d_in[0];
    const float* wk = (const float*)d_in[1];
    const float* bk = (const float*)d_in[2];
    float* o = (float*)d_out;

    ushort_t* kern_ws = (ushort_t*)d_ws;
    ushort_t* xT      = (ushort_t*)((char*)d_ws + XT_OFF);
    unsigned* wbf     = (unsigned*)((char*)d_ws + WBF_OFF);

    cvt_xT<<<dim3(65, 4, B_), dim3(256), 0, stream>>>(x, wk, xT, wbf);
    kern_gemm<<<dim3(32, 7, B_), dim3(256), 0, stream>>>(
        xT, (const ushort_t*)wbf, bk, kern_ws);
    inv_apply<<<dim3(8, 16, B_), dim3(512), 0, stream>>>(x, kern_ws, o);
}

// Round 6
// 151.834 us; speedup vs baseline: 1.0548x; 1.0548x over previous
//
#include <hip/hip_runtime.h>

// Involution2d, 2-kernel: K0 converts/transposes; K1 fuses GEMM+apply.
// K0: x f32 [b][ch][px] -> xT bf16 [b][px][ch]; w -> bf16.
// K1: per block (b, g, 4-row x 64-px tile):
//     GEMM (reg-dbuf, LDS-free): kern[49 x 256px] = W_g @ xT + bias -> LDS bf16
//     apply: out[c][p] = sum_{7x7} halo[c][p+off] * kern[koff][p]
// bid = g*64 + (b*16+tile): same-tile different-g blocks land on same XCD (L2 xT reuse).

#define B_   4
#define C_   256
#define HW_  4096
#define G_   16
#define KK_  49
#define M_   784
#define KS_  7
#define PD_  3

#define XT_BYTES    (B_*HW_*C_*2)            //  8,388,608
#define WBF_OFF     XT_BYTES

#define SK   264                             // kern_lds stride (bf16)
#define HSTR 72                              // halo row stride (f32)

typedef __attribute__((ext_vector_type(8))) short bf16x8;
typedef __attribute__((ext_vector_type(4))) float f32x4;
typedef unsigned short ushort_t;

__device__ inline unsigned f2bf(float f) {            // RNE fp32->bf16
    unsigned u = __float_as_uint(f);
    u += 0x7FFF + ((u >> 16) & 1);
    return u >> 16;
}
__device__ inline float bf2f(unsigned short s) {
    return __uint_as_float(((unsigned)s) << 16);
}

// ---------------- K0: transpose-convert x -> xT bf16; convert w ----------------
__global__ __launch_bounds__(256)
void cvt_xT(const float* __restrict__ x, const float* __restrict__ wk,
            ushort_t* __restrict__ xT, unsigned* __restrict__ wbf) {
    const int t = threadIdx.x;
    if (blockIdx.x == 64) {   // W convert: 100352 f32 pairs, 16 slices
        const int slice = blockIdx.z * 4 + blockIdx.y;
        const float2* wk2 = (const float2*)wk;
        const int base = slice * 6272;
        for (int k = t; k < 6272; k += 256) {
            float2 v = wk2[base + k];
            wbf[base + k] = f2bf(v.x) | (f2bf(v.y) << 16);
        }
        return;
    }
    __shared__ float tile[64][65];
    const int p0 = blockIdx.x * 64;
    const int c0 = blockIdx.y * 64;
    const int b  = blockIdx.z;
    const int px_r = t & 63;
    #pragma unroll
    for (int i = 0; i < 16; ++i) {
        int ch = (t >> 6) + i * 4;
        tile[ch][px_r] = x[((size_t)(b * C_ + c0 + ch) << 12) + p0 + px_r];
    }
    __syncthreads();
    const int px  = t >> 2;
    const int seg = t & 3;
    unsigned u[8];
    #pragma unroll
    for (int j = 0; j < 8; ++j) {
        float a0 = tile[seg * 16 + 2 * j][px];
        float a1 = tile[seg * 16 + 2 * j + 1][px];
        u[j] = f2bf(a0) | (f2bf(a1) << 16);
    }
    unsigned* dst = (unsigned*)(xT + ((size_t)((b << 12) + p0 + px)) * C_ + c0 + seg * 16);
    ((uint4*)dst)[0] = make_uint4(u[0], u[1], u[2], u[3]);
    ((uint4*)dst)[1] = make_uint4(u[4], u[5], u[6], u[7]);
}

// ---------------- K1: fused GEMM + apply ----------------
__global__ __launch_bounds__(256, 3)
void inv_fused(const ushort_t* __restrict__ xT,
               const ushort_t* __restrict__ wbf,
               const float* __restrict__ bk,
               const float* __restrict__ x,
               float* __restrict__ out) {
    __shared__ ushort_t kern_lds[KK_ * SK];      // 25,872 B
    __shared__ float    halo[8 * 10 * HSTR];     // 23,040 B

    const int bid  = blockIdx.x;
    const int g    = bid >> 6;
    const int b    = (bid >> 4) & 3;
    const int tile = bid & 15;
    const int gy0  = tile * 4;
    const int p0   = gy0 * 64;                   // linear pixel base, 256 px tile

    const int tid  = threadIdx.x;
    const int wv   = tid >> 6;
    const int ln15 = tid & 15;
    const int quad = (tid & 63) >> 4;

    // ---- GEMM phase: wave wv owns n-cols p0+wv*64 (4 n-tiles), 4 m-tiles ----
    f32x4 acc[16];
    #pragma unroll
    for (int i = 0; i < 16; ++i) acc[i] = (f32x4){0.f, 0.f, 0.f, 0.f};

    const ushort_t* ap[4];
    #pragma unroll
    for (int mt = 0; mt < 4; ++mt) {
        int r = mt * 16 + ln15; if (r > KK_ - 1) r = KK_ - 1;   // clamp pad rows
        ap[mt] = wbf + (size_t)(g * KK_ + r) * C_ + quad * 8;
    }
    const ushort_t* bp = xT + ((size_t)((b << 12) + p0 + wv * 64 + ln15)) * C_ + quad * 8;

    bf16x8 af[2][4], bf[2][4];
    #pragma unroll
    for (int mt = 0; mt < 4; ++mt) af[0][mt] = *(const bf16x8*)(ap[mt]);
    #pragma unroll
    for (int nt = 0; nt < 4; ++nt) bf[0][nt] = *(const bf16x8*)(bp + nt * 16 * C_);

    #pragma unroll
    for (int k = 0; k < 8; ++k) {
        const int cur = k & 1, nxt = cur ^ 1;
        if (k < 7) {
            const int cc = (k + 1) * 32;
            #pragma unroll
            for (int mt = 0; mt < 4; ++mt)
                af[nxt][mt] = *(const bf16x8*)(ap[mt] + cc);
            #pragma unroll
            for (int nt = 0; nt < 4; ++nt)
                bf[nxt][nt] = *(const bf16x8*)(bp + nt * 16 * C_ + cc);
        }
        #pragma unroll
        for (int mt = 0; mt < 4; ++mt) {
            #pragma unroll
            for (int nt = 0; nt < 4; ++nt) {
                acc[mt * 4 + nt] = __builtin_amdgcn_mfma_f32_16x16x32_bf16(
                    af[cur][mt], bf[cur][nt], acc[mt * 4 + nt], 0, 0, 0);
            }
        }
    }

    // epilogue: D[m=quad*4+r][n=ln15]; bias, bf16 into LDS
    #pragma unroll
    for (int mt = 0; mt < 4; ++mt) {
        #pragma unroll
        for (int r = 0; r < 4; ++r) {
            const int m = mt * 16 + quad * 4 + r;
            if (m < KK_) {
                const float bias = bk[g * KK_ + m];
                #pragma unroll
                for (int nt = 0; nt < 4; ++nt) {
                    kern_lds[m * SK + wv * 64 + nt * 16 + ln15] =
                        (ushort_t)f2bf(acc[mt * 4 + nt][r] + bias);
                }
            }
        }
    }
    __syncthreads();

    // ---- apply phase: thread = pixel tid (4 rows x 64 px) ----
    float kernv[KK_];
    #pragma unroll
    for (int kx = 0; kx < KK_; ++kx) kernv[kx] = bf2f(kern_lds[kx * SK + tid]);

    const int py = tid >> 6;
    const int px = tid & 63;

    #pragma unroll 1
    for (int hb = 0; hb < 2; ++hb) {
        if (hb) __syncthreads();
        const int cbase = g * 16 + hb * 8;
        for (int e = tid; e < 8 * 10 * 70; e += 256) {
            int ch  = e / 700;
            int rem = e - ch * 700;
            int hy  = rem / 70;
            int hx  = rem - hy * 70;
            int sy  = gy0 + hy - PD_;
            int sx  = hx - PD_;
            float v = 0.f;
            if (sy >= 0 && sy < 64 && sx >= 0 && sx < 64)
                v = x[((size_t)(b * C_ + cbase + ch) << 12) + sy * 64 + sx];
            halo[ch * (10 * HSTR) + hy * HSTR + hx] = v;
        }
        __syncthreads();

        #pragma unroll 1
        for (int c = 0; c < 8; ++c) {
            const float* xs = &halo[c * (10 * HSTR) + py * HSTR + px];
            float a = 0.f;
            #pragma unroll
            for (int kh = 0; kh < KS_; ++kh) {
                #pragma unroll
                for (int kw = 0; kw < KS_; ++kw) {
                    a = fmaf(xs[kh * HSTR + kw], kernv[kh * KS_ + kw], a);
                }
            }
            out[((size_t)(b * C_ + cbase + c) << 12) + p0 + tid] = a;
        }
    }
}

extern "C" void kernel_launch(void* const* d_in, const int* in_sizes, int n_in,
                              void* d_out, int out_size, void* d_ws, size_t ws_size,
                              hipStream_t stream) {
    const float* x  = (const float*)d_in[0];
    const float* wk = (const float*)d_in[1];
    const float* bk = (const float*)d_in[2];
    float* o = (float*)d_out;

    ushort_t* xT  = (ushort_t*)d_ws;
    unsigned* wbf = (unsigned*)((char*)d_ws + WBF_OFF);

    cvt_xT<<<dim3(65, 4, B_), dim3(256), 0, stream>>>(x, wk, xT, wbf);
    inv_fused<<<dim3(1024), dim3(256), 0, stream>>>(
        xT, (const ushort_t*)wbf, bk, x, o);
}

// Round 7
// 127.989 us; speedup vs baseline: 1.2513x; 1.1863x over previous
//
#include <hip/hip_runtime.h>

// Involution2d, 2-kernel: K0 converts/transposes; K1 fuses GEMM+apply.
// K0: x f32 [b][ch][px] -> xT bf16 [b][px][ch]; w -> bf16.
// K1 per block (b, g, 4-row x 64-px tile):
//   GEMM (reg-dbuf, LDS-free): kern[49 x 256px] = W_g @ xT + bias -> kern2 LDS
//     kern2 layout: [pixel 0..255][56 bf16] (49 used) -> per-thread b128 reads
//   apply: halo as channel-paired bf16 [cp][10 rows][71 cols] (2 ch/dword):
//     each ds_read_b32 feeds 2 channels' fma -> ~2x fewer LDS instructions.
// LDS 40,032 B -> 4 blocks/CU (launch_bounds(256,4)).

#define B_   4
#define C_   256
#define G_   16
#define KK_  49
#define KS_  7
#define PD_  3

#define XT_BYTES  (B_*4096*C_*2)
#define WBF_OFF   XT_BYTES

#define SKW   28            // kern2 row stride, dwords (=56 bf16, 49 used)
#define HR_   71            // halo row stride, dwords (70 cols + 1 pad)
#define HCPS  (10*HR_)      // per channel-pair halo block (710 dw)

typedef __attribute__((ext_vector_type(8))) short bf16x8;
typedef __attribute__((ext_vector_type(4))) float f32x4;
typedef unsigned short ushort_t;

__device__ inline unsigned f2bf(float f) {            // RNE fp32->bf16
    unsigned u = __float_as_uint(f);
    u += 0x7FFF + ((u >> 16) & 1);
    return u >> 16;
}

// ---------------- K0: transpose-convert x -> xT bf16; convert w ----------------
__global__ __launch_bounds__(256)
void cvt_xT(const float* __restrict__ x, const float* __restrict__ wk,
            ushort_t* __restrict__ xT, unsigned* __restrict__ wbf) {
    const int t = threadIdx.x;
    if (blockIdx.x == 64) {   // W convert: 100352 f32 pairs, 16 slices
        const int slice = blockIdx.z * 4 + blockIdx.y;
        const float2* wk2 = (const float2*)wk;
        const int base = slice * 6272;
        for (int k = t; k < 6272; k += 256) {
            float2 v = wk2[base + k];
            wbf[base + k] = f2bf(v.x) | (f2bf(v.y) << 16);
        }
        return;
    }
    __shared__ float tile[64][65];
    const int p0 = blockIdx.x * 64;
    const int c0 = blockIdx.y * 64;
    const int b  = blockIdx.z;
    const int px_r = t & 63;
    #pragma unroll
    for (int i = 0; i < 16; ++i) {
        int ch = (t >> 6) + i * 4;
        tile[ch][px_r] = x[((size_t)(b * C_ + c0 + ch) << 12) + p0 + px_r];
    }
    __syncthreads();
    const int px  = t >> 2;
    const int seg = t & 3;
    unsigned u[8];
    #pragma unroll
    for (int j = 0; j < 8; ++j) {
        float a0 = tile[seg * 16 + 2 * j][px];
        float a1 = tile[seg * 16 + 2 * j + 1][px];
        u[j] = f2bf(a0) | (f2bf(a1) << 16);
    }
    unsigned* dst = (unsigned*)(xT + ((size_t)((b << 12) + p0 + px)) * C_ + c0 + seg * 16);
    ((uint4*)dst)[0] = make_uint4(u[0], u[1], u[2], u[3]);
    ((uint4*)dst)[1] = make_uint4(u[4], u[5], u[6], u[7]);
}

// ---------------- K1: fused GEMM + apply ----------------
__global__ __launch_bounds__(256, 4)
void inv_fused(const ushort_t* __restrict__ xT,
               const ushort_t* __restrict__ wbf,
               const float* __restrict__ bk,
               const float* __restrict__ x,
               float* __restrict__ out) {
    __shared__ unsigned kern2[256 * SKW];     // 28,672 B  [pixel][28 dw]
    __shared__ unsigned halo2[4 * HCPS];      // 11,360 B  [cp][10][71]

    const int bid  = blockIdx.x;
    const int g    = bid >> 6;
    const int b    = (bid >> 4) & 3;
    const int tile = bid & 15;
    const int gy0  = tile * 4;
    const int p0   = gy0 * 64;

    const int tid  = threadIdx.x;
    const int wv   = tid >> 6;
    const int ln15 = tid & 15;
    const int quad = (tid & 63) >> 4;

    // ---- GEMM: wave wv owns n-cols p0+wv*64 (4 n-tiles) x 4 m-tiles ----
    f32x4 acc[16];
    #pragma unroll
    for (int i = 0; i < 16; ++i) acc[i] = (f32x4){0.f, 0.f, 0.f, 0.f};

    const ushort_t* ap[4];
    #pragma unroll
    for (int mt = 0; mt < 4; ++mt) {
        int r = mt * 16 + ln15; if (r > KK_ - 1) r = KK_ - 1;   // clamp pad rows
        ap[mt] = wbf + (size_t)(g * KK_ + r) * C_ + quad * 8;
    }
    const ushort_t* bp = xT + ((size_t)((b << 12) + p0 + wv * 64 + ln15)) * C_ + quad * 8;

    bf16x8 af[2][4], bf[2][4];
    #pragma unroll
    for (int mt = 0; mt < 4; ++mt) af[0][mt] = *(const bf16x8*)(ap[mt]);
    #pragma unroll
    for (int nt = 0; nt < 4; ++nt) bf[0][nt] = *(const bf16x8*)(bp + nt * 16 * C_);

    #pragma unroll
    for (int k = 0; k < 8; ++k) {
        const int cur = k & 1, nxt = cur ^ 1;
        if (k < 7) {
            const int cc = (k + 1) * 32;
            #pragma unroll
            for (int mt = 0; mt < 4; ++mt)
                af[nxt][mt] = *(const bf16x8*)(ap[mt] + cc);
            #pragma unroll
            for (int nt = 0; nt < 4; ++nt)
                bf[nxt][nt] = *(const bf16x8*)(bp + nt * 16 * C_ + cc);
        }
        #pragma unroll
        for (int mt = 0; mt < 4; ++mt) {
            #pragma unroll
            for (int nt = 0; nt < 4; ++nt) {
                acc[mt * 4 + nt] = __builtin_amdgcn_mfma_f32_16x16x32_bf16(
                    af[cur][mt], bf[cur][nt], acc[mt * 4 + nt], 0, 0, 0);
            }
        }
    }

    // ---- epilogue: D[m=quad*4+r][n=ln15] -> kern2[pixel][m] bf16, b64 writes ----
    #pragma unroll
    for (int mt = 0; mt < 3; ++mt) {                      // m = mt*16+quad*4+r <= 47
        const int m0 = mt * 16 + quad * 4;
        const float b0 = bk[g * KK_ + m0],     b1 = bk[g * KK_ + m0 + 1];
        const float b2 = bk[g * KK_ + m0 + 2], b3 = bk[g * KK_ + m0 + 3];
        #pragma unroll
        for (int nt = 0; nt < 4; ++nt) {
            const int p = wv * 64 + nt * 16 + ln15;
            uint2 d;
            d.x = f2bf(acc[mt * 4 + nt][0] + b0) | (f2bf(acc[mt * 4 + nt][1] + b1) << 16);
            d.y = f2bf(acc[mt * 4 + nt][2] + b2) | (f2bf(acc[mt * 4 + nt][3] + b3) << 16);
            *(uint2*)&kern2[p * SKW + mt * 8 + quad * 2] = d;
        }
    }
    if (quad == 0) {                                      // mt=3: only m=48 valid
        const float b48 = bk[g * KK_ + 48];
        #pragma unroll
        for (int nt = 0; nt < 4; ++nt) {
            const int p = wv * 64 + nt * 16 + ln15;
            kern2[p * SKW + 24] = f2bf(acc[12 + nt][0] + b48);   // lo=m48, hi=0
        }
    }
    __syncthreads();

    // ---- my pixel's 49 kern values: 7x ds_read_b128 + unpack ----
    float kv[KK_];
    {
        const uint4* kr = (const uint4*)&kern2[tid * SKW];
        unsigned kd[28];
        #pragma unroll
        for (int q = 0; q < 7; ++q) {
            uint4 h = kr[q];
            kd[4*q] = h.x; kd[4*q+1] = h.y; kd[4*q+2] = h.z; kd[4*q+3] = h.w;
        }
        #pragma unroll
        for (int k = 0; k < KK_; ++k) {
            unsigned d = kd[k >> 1];
            kv[k] = __uint_as_float((k & 1) ? (d & 0xffff0000u) : (d << 16));
        }
    }

    // ---- apply: 2 batches of 8 channels (4 channel-pairs) ----
    const int py = tid >> 6, px = tid & 63;
    #pragma unroll 1
    for (int hb = 0; hb < 2; ++hb) {
        if (hb) __syncthreads();
        const int cbase = g * 16 + hb * 8;
        // stage: dword = bf16(ch 2cp) | bf16(ch 2cp+1) at (row,col)
        for (int e = tid; e < 4 * HCPS; e += 256) {
            int cp  = e / HCPS;
            int rem = e - cp * HCPS;
            int row = rem / HR_;
            int col = rem - row * HR_;       // col 70 = pad slot (stores 0)
            int sy = gy0 + row - PD_;
            int sx = col - PD_;
            float v0 = 0.f, v1 = 0.f;
            if (sy >= 0 && sy < 64 && sx >= 0 && sx < 64) {
                const float* xp = x + ((size_t)(b * C_ + cbase + 2 * cp) << 12) + sy * 64 + sx;
                v0 = xp[0];
                v1 = xp[4096];
            }
            halo2[e] = f2bf(v0) | (f2bf(v1) << 16);
        }
        __syncthreads();

        #pragma unroll 1
        for (int cp = 0; cp < 4; ++cp) {
            float a0 = 0.f, a1 = 0.f;
            #pragma unroll
            for (int kh = 0; kh < KS_; ++kh) {
                const unsigned* hr = &halo2[cp * HCPS + (py + kh) * HR_ + px];
                #pragma unroll
                for (int kw = 0; kw < KS_; ++kw) {
                    unsigned d = hr[kw];
                    float kk = kv[kh * KS_ + kw];
                    a0 = fmaf(__uint_as_float(d << 16),          kk, a0);
                    a1 = fmaf(__uint_as_float(d & 0xffff0000u),  kk, a1);
                }
            }
            size_t o = ((size_t)(b * C_ + cbase + 2 * cp) << 12) + p0 + tid;
            out[o] = a0;
            out[o + 4096] = a1;
        }
    }
}

extern "C" void kernel_launch(void* const* d_in, const int* in_sizes, int n_in,
                              void* d_out, int out_size, void* d_ws, size_t ws_size,
                              hipStream_t stream) {
    const float* x  = (const float*)d_in[0];
    const float* wk = (const float*)d_in[1];
    const float* bk = (const float*)d_in[2];
    float* o = (float*)d_out;

    ushort_t* xT  = (ushort_t*)d_ws;
    unsigned* wbf = (unsigned*)((char*)d_ws + WBF_OFF);

    cvt_xT<<<dim3(65, 4, B_), dim3(256), 0, stream>>>(x, wk, xT, wbf);
    inv_fused<<<dim3(1024), dim3(256), 0, stream>>>(
        xT, (const ushort_t*)wbf, bk, x, o);
}

// Round 8
// 117.663 us; speedup vs baseline: 1.3611x; 1.0878x over previous
//
#include <hip/hip_runtime.h>

// Involution2d, 2-kernel: K0 converts/transposes; K1 fuses GEMM+apply.
// K0: x f32 [b][ch][px] -> xT bf16 [b][px][ch]; w -> bf16.
// K1 per block (b, g, 4-row x 64-px tile):
//   GEMM (reg-dbuf, LDS-free): kern[49 x 256px] = W_g @ xT + bias -> kern2 LDS
//     kern2 layout: [pixel 0..255][56 bf16] -> per-thread b128 reads
//   apply: halo packed 8 channels/column: [row][col][4dw] (bf16 pairs);
//     one ds_read_b128 per tap feeds 8 channels' fma (98 b128/thread total).
// LDS 39,872 B -> 4 blocks/CU.

#define B_   4
#define C_   256
#define G_   16
#define KK_  49
#define KS_  7
#define PD_  3

#define XT_BYTES  (B_*4096*C_*2)
#define WBF_OFF   XT_BYTES

#define SKW   28            // kern2 row stride, dwords (=56 bf16, 49 used)
#define HC_   70            // halo cols
#define HPOS  (10*HC_)      // halo positions per batch (700)

typedef __attribute__((ext_vector_type(8))) short bf16x8;
typedef __attribute__((ext_vector_type(4))) float f32x4;
typedef unsigned short ushort_t;

__device__ inline unsigned f2bf(float f) {            // RNE fp32->bf16
    unsigned u = __float_as_uint(f);
    u += 0x7FFF + ((u >> 16) & 1);
    return u >> 16;
}

// ---------------- K0: transpose-convert x -> xT bf16; convert w ----------------
__global__ __launch_bounds__(256)
void cvt_xT(const float* __restrict__ x, const float* __restrict__ wk,
            ushort_t* __restrict__ xT, unsigned* __restrict__ wbf) {
    const int t = threadIdx.x;
    if (blockIdx.x == 64) {   // W convert: 100352 f32 pairs, 16 slices
        const int slice = blockIdx.z * 4 + blockIdx.y;
        const float2* wk2 = (const float2*)wk;
        const int base = slice * 6272;
        for (int k = t; k < 6272; k += 256) {
            float2 v = wk2[base + k];
            wbf[base + k] = f2bf(v.x) | (f2bf(v.y) << 16);
        }
        return;
    }
    __shared__ float tile[64][65];
    const int p0 = blockIdx.x * 64;
    const int c0 = blockIdx.y * 64;
    const int b  = blockIdx.z;
    const int px_r = t & 63;
    #pragma unroll
    for (int i = 0; i < 16; ++i) {
        int ch = (t >> 6) + i * 4;
        tile[ch][px_r] = x[((size_t)(b * C_ + c0 + ch) << 12) + p0 + px_r];
    }
    __syncthreads();
    const int px  = t >> 2;
    const int seg = t & 3;
    unsigned u[8];
    #pragma unroll
    for (int j = 0; j < 8; ++j) {
        float a0 = tile[seg * 16 + 2 * j][px];
        float a1 = tile[seg * 16 + 2 * j + 1][px];
        u[j] = f2bf(a0) | (f2bf(a1) << 16);
    }
    unsigned* dst = (unsigned*)(xT + ((size_t)((b << 12) + p0 + px)) * C_ + c0 + seg * 16);
    ((uint4*)dst)[0] = make_uint4(u[0], u[1], u[2], u[3]);
    ((uint4*)dst)[1] = make_uint4(u[4], u[5], u[6], u[7]);
}

// ---------------- K1: fused GEMM + apply ----------------
__global__ __launch_bounds__(256, 4)
void inv_fused(const ushort_t* __restrict__ xT,
               const ushort_t* __restrict__ wbf,
               const float* __restrict__ bk,
               const float* __restrict__ x,
               float* __restrict__ out) {
    __shared__ unsigned kern2[256 * SKW];     // 28,672 B  [pixel][28 dw]
    __shared__ unsigned halo4[HPOS * 4];      // 11,200 B  [row][col][4dw=8ch]

    const int bid  = blockIdx.x;
    const int g    = bid >> 6;
    const int b    = (bid >> 4) & 3;
    const int tile = bid & 15;
    const int gy0  = tile * 4;
    const int p0   = gy0 * 64;

    const int tid  = threadIdx.x;
    const int wv   = tid >> 6;
    const int ln15 = tid & 15;
    const int quad = (tid & 63) >> 4;

    // ---- GEMM: wave wv owns n-cols p0+wv*64 (4 n-tiles) x 4 m-tiles ----
    f32x4 acc[16];
    #pragma unroll
    for (int i = 0; i < 16; ++i) acc[i] = (f32x4){0.f, 0.f, 0.f, 0.f};

    const ushort_t* ap[4];
    #pragma unroll
    for (int mt = 0; mt < 4; ++mt) {
        int r = mt * 16 + ln15; if (r > KK_ - 1) r = KK_ - 1;   // clamp pad rows
        ap[mt] = wbf + (size_t)(g * KK_ + r) * C_ + quad * 8;
    }
    const ushort_t* bp = xT + ((size_t)((b << 12) + p0 + wv * 64 + ln15)) * C_ + quad * 8;

    bf16x8 af[2][4], bf[2][4];
    #pragma unroll
    for (int mt = 0; mt < 4; ++mt) af[0][mt] = *(const bf16x8*)(ap[mt]);
    #pragma unroll
    for (int nt = 0; nt < 4; ++nt) bf[0][nt] = *(const bf16x8*)(bp + nt * 16 * C_);

    #pragma unroll
    for (int k = 0; k < 8; ++k) {
        const int cur = k & 1, nxt = cur ^ 1;
        if (k < 7) {
            const int cc = (k + 1) * 32;
            #pragma unroll
            for (int mt = 0; mt < 4; ++mt)
                af[nxt][mt] = *(const bf16x8*)(ap[mt] + cc);
            #pragma unroll
            for (int nt = 0; nt < 4; ++nt)
                bf[nxt][nt] = *(const bf16x8*)(bp + nt * 16 * C_ + cc);
        }
        #pragma unroll
        for (int mt = 0; mt < 4; ++mt) {
            #pragma unroll
            for (int nt = 0; nt < 4; ++nt) {
                acc[mt * 4 + nt] = __builtin_amdgcn_mfma_f32_16x16x32_bf16(
                    af[cur][mt], bf[cur][nt], acc[mt * 4 + nt], 0, 0, 0);
            }
        }
    }

    // ---- epilogue: D[m=quad*4+r][n=ln15] -> kern2[pixel][m] bf16, b64 writes ----
    #pragma unroll
    for (int mt = 0; mt < 3; ++mt) {                      // m = mt*16+quad*4+r <= 47
        const int m0 = mt * 16 + quad * 4;
        const float b0 = bk[g * KK_ + m0],     b1 = bk[g * KK_ + m0 + 1];
        const float b2 = bk[g * KK_ + m0 + 2], b3 = bk[g * KK_ + m0 + 3];
        #pragma unroll
        for (int nt = 0; nt < 4; ++nt) {
            const int p = wv * 64 + nt * 16 + ln15;
            uint2 d;
            d.x = f2bf(acc[mt * 4 + nt][0] + b0) | (f2bf(acc[mt * 4 + nt][1] + b1) << 16);
            d.y = f2bf(acc[mt * 4 + nt][2] + b2) | (f2bf(acc[mt * 4 + nt][3] + b3) << 16);
            *(uint2*)&kern2[p * SKW + mt * 8 + quad * 2] = d;
        }
    }
    if (quad == 0) {                                      // mt=3: only m=48 valid
        const float b48 = bk[g * KK_ + 48];
        #pragma unroll
        for (int nt = 0; nt < 4; ++nt) {
            const int p = wv * 64 + nt * 16 + ln15;
            kern2[p * SKW + 24] = f2bf(acc[12 + nt][0] + b48);   // lo=m48, hi=0
        }
    }
    __syncthreads();

    // ---- my pixel's 49 kern values: 7x ds_read_b128 + unpack ----
    float kv[KK_];
    {
        const uint4* kr = (const uint4*)&kern2[tid * SKW];
        unsigned kd[28];
        #pragma unroll
        for (int q = 0; q < 7; ++q) {
            uint4 h = kr[q];
            kd[4*q] = h.x; kd[4*q+1] = h.y; kd[4*q+2] = h.z; kd[4*q+3] = h.w;
        }
        #pragma unroll
        for (int k = 0; k < KK_; ++k) {
            unsigned d = kd[k >> 1];
            kv[k] = __uint_as_float((k & 1) ? (d & 0xffff0000u) : (d << 16));
        }
    }

    // ---- apply: 2 batches of 8 channels, packed 8ch per 16B column ----
    const int py = tid >> 6, px = tid & 63;
    #pragma unroll 1
    for (int hb = 0; hb < 2; ++hb) {
        if (hb) __syncthreads();
        const int cbase = g * 16 + hb * 8;
        // stage: position (row,col) -> 4 dwords = 8 channels (bf16 pairs)
        for (int e = tid; e < HPOS; e += 256) {
            int row = e / HC_;
            int col = e - row * HC_;
            int sy = gy0 + row - PD_;
            int sx = col - PD_;
            unsigned d0 = 0, d1 = 0, d2 = 0, d3 = 0;
            if (sy >= 0 && sy < 64 && sx >= 0 && sx < 64) {
                const float* xp = x + ((size_t)(b * C_ + cbase) << 12) + sy * 64 + sx;
                d0 = f2bf(xp[0])             | (f2bf(xp[1 << 12]) << 16);
                d1 = f2bf(xp[2 << 12])       | (f2bf(xp[3 << 12]) << 16);
                d2 = f2bf(xp[4 << 12])       | (f2bf(xp[5 << 12]) << 16);
                d3 = f2bf(xp[6 << 12])       | (f2bf(xp[7 << 12]) << 16);
            }
            *(uint4*)&halo4[e * 4] = make_uint4(d0, d1, d2, d3);
        }
        __syncthreads();

        float a[8];
        #pragma unroll
        for (int q = 0; q < 8; ++q) a[q] = 0.f;
        #pragma unroll
        for (int kh = 0; kh < KS_; ++kh) {
            const uint4* hr = (const uint4*)&halo4[(((py + kh) * HC_) + px) * 4];
            #pragma unroll
            for (int kw = 0; kw < KS_; ++kw) {
                uint4 hv = hr[kw];
                float kk = kv[kh * KS_ + kw];
                a[0] = fmaf(__uint_as_float(hv.x << 16),          kk, a[0]);
                a[1] = fmaf(__uint_as_float(hv.x & 0xffff0000u),  kk, a[1]);
                a[2] = fmaf(__uint_as_float(hv.y << 16),          kk, a[2]);
                a[3] = fmaf(__uint_as_float(hv.y & 0xffff0000u),  kk, a[3]);
                a[4] = fmaf(__uint_as_float(hv.z << 16),          kk, a[4]);
                a[5] = fmaf(__uint_as_float(hv.z & 0xffff0000u),  kk, a[5]);
                a[6] = fmaf(__uint_as_float(hv.w << 16),          kk, a[6]);
                a[7] = fmaf(__uint_as_float(hv.w & 0xffff0000u),  kk, a[7]);
            }
        }
        const size_t o = ((size_t)(b * C_ + cbase) << 12) + p0 + tid;
        #pragma unroll
        for (int q = 0; q < 8; ++q)
            out[o + ((size_t)q << 12)] = a[q];
    }
}

extern "C" void kernel_launch(void* const* d_in, const int* in_sizes, int n_in,
                              void* d_out, int out_size, void* d_ws, size_t ws_size,
                              hipStream_t stream) {
    const float* x  = (const float*)d_in[0];
    const float* wk = (const float*)d_in[1];
    const float* bk = (const float*)d_in[2];
    float* o = (float*)d_out;

    ushort_t* xT  = (ushort_t*)d_ws;
    unsigned* wbf = (unsigned*)((char*)d_ws + WBF_OFF);

    cvt_xT<<<dim3(65, 4, B_), dim3(256), 0, stream>>>(x, wk, xT, wbf);
    inv_fused<<<dim3(1024), dim3(256), 0, stream>>>(
        xT, (const ushort_t*)wbf, bk, x, o);
}